// Round 4
// baseline (5127.032 us; speedup 1.0000x reference)
//
#include <hip/hip_runtime.h>
#include <hip/hip_bf16.h>

// BiLSTM classifier, MI355X — round 4 (low-workspace rewrite).
// probe (MFMA A/B k-layout self-test -> flag in ws, + duration side-channel)
// -> prep (pack Wh/Wi fp32 -> bf16 MFMA B-fragments per flag)
// -> embed (emb gather -> x as MFMA A-fragments, 32 MB)
// -> rnn (32 persistent blocks, batch-partitioned; per step z = bias + x@Wi
//         + h@Wh as 12 unified K=32 chunks, B-frags streamed from L2 with
//         rotate-3 buffering; gates on VALU; h double-buffered in LDS)
// -> head (feat@Wd+bd).
// ws need: ~35.7 MB (guarded against smaller ws_size).

typedef __attribute__((ext_vector_type(8))) short bf16x8;
typedef __attribute__((ext_vector_type(4))) float f32x4;

#define S_LEN 512

// ws layout (bytes)
#define XF_OFF   0ULL
#define XF_SZ    (512ULL*16*4*64*16)           // 33,554,432
#define WHF_OFF  (XF_OFF + XF_SZ)
#define WHF_SZ   (2ULL*8*8*8*64*16)            // 1,048,576
#define WIF_OFF  (WHF_OFF + WHF_SZ)
#define WIF_SZ   (2ULL*8*4*8*64*16)            // 524,288
#define FEAT_OFF (WIF_OFF + WIF_SZ)
#define FEAT_SZ  (256ULL*512*4)                // 524,288
#define FLAG_OFF (FEAT_OFF + FEAT_SZ)
#define WS_NEED  (FLAG_OFF + 16)

__device__ __forceinline__ short f2bf(float f){
  union { float f; unsigned u; } v; v.f = f;
  unsigned u = v.u;
  u += 0x7fffu + ((u >> 16) & 1u);   // RNE
  return (short)(u >> 16);
}
__device__ __forceinline__ float fsig(float x){
  float t = __builtin_amdgcn_exp2f(-1.44269504f * x);
  return __builtin_amdgcn_rcpf(1.0f + t);
}
__device__ __forceinline__ float ftanh(float x){
  float t = __builtin_amdgcn_exp2f(2.88539008f * x);   // e^{2x}
  return 1.0f - 2.0f * __builtin_amdgcn_rcpf(1.0f + t);
}
__device__ __forceinline__ int pack2(float a, float b){
  return (int)(unsigned short)f2bf(a) | ((int)(unsigned short)f2bf(b) << 16);
}
// k-offset within a K=32 chunk for input-fragment element j, lane-half h=(lane>>4).
// flag=1: contiguous (k = 8h+j). flag=0: split halves (k = 4h+j | 16+4h+(j-4)).
__device__ __forceinline__ int koff(int flag, int h, int j){
  return flag ? (8*h + j) : (j < 4 ? 4*h + j : 16 + 4*h + (j-4));
}
// Assemble an A-fragment (8 bf16) from a row of 16-bit LDS at colbase.
__device__ __forceinline__ bf16x8 loadA(const short* p, int colbase, int h, int flag){
  if (flag){
    return *(const bf16x8*)(p + colbase + 8*h);
  } else {
    short4 lo = *(const short4*)(p + colbase + 4*h);
    short4 hi = *(const short4*)(p + colbase + 16 + 4*h);
    bf16x8 r;
    r[0]=lo.x; r[1]=lo.y; r[2]=lo.z; r[3]=lo.w;
    r[4]=hi.x; r[5]=hi.y; r[6]=hi.z; r[7]=hi.w;
    return r;
  }
}

// ---------------- probe: decide MFMA input-fragment layout ------------------
__device__ __noinline__ void spin_units(int n){
  float x = 1.5f;
  for (int i=0; i<n*300; i++) x = __builtin_amdgcn_rcpf(x + 1.0f);
  asm volatile("" :: "v"(x));
}
__global__ __launch_bounds__(64) void probe_kernel(char* ws){
  int l = threadIdx.x;
  // exact scalar reference, D[m][n], m = 4*(l>>4)+r, n = l&15 (verified C/D layout)
  float dref[4]; int n = l & 15;
  #pragma unroll
  for (int r=0;r<4;r++){
    int m = 4*(l>>4) + r; float s = 0.f;
    for (int k=0;k<32;k++)
      s += (0.25f*(float)((m*7+k*3)%5-2)) * (0.125f*(float)((k*5+n*11)%7-3));
    dref[r] = s;
  }
  f32x4 zero = {0.f,0.f,0.f,0.f};
  int bad[2];
  #pragma unroll
  for (int cand=0; cand<2; cand++){          // cand: 0=split, 1=contiguous
    bf16x8 a, b;
    #pragma unroll
    for (int j=0;j<8;j++){
      int k = koff(cand, l>>4, j);
      a[j] = f2bf(0.25f*(float)(((l&15)*7+k*3)%5-2));
      b[j] = f2bf(0.125f*(float)((k*5+(l&15)*11)%7-3));
    }
    f32x4 d = __builtin_amdgcn_mfma_f32_16x16x32_bf16(a,b,zero,0,0,0);
    int bb = 0;
    #pragma unroll
    for (int r=0;r<4;r++) bb |= (fabsf(d[r]-dref[r]) > 1e-4f) ? 1 : 0;
    bad[cand] = bb;
  }
  unsigned long long B2 = __ballot(bad[1]);  // contiguous wrong?
  unsigned long long B1 = __ballot(bad[0]);  // split wrong?
  if (l == 0){
    int flag = (B2 == 0ULL) ? 1 : 0;         // prefer contiguous if it verifies
    *(int*)(ws + FLAG_OFF) = flag;
  }
  // duration side-channel: +10us => split is real; +30us => contiguous is real
  if (B2) spin_units(10);
  if (B1) spin_units(30);
}

// ---------------- prep: pack Wh,Wi (fp32) -> bf16 MFMA B-fragments ----------
// Whf: [dir][w][ks 0..7][tile 0..7][lane][16B], elem j -> Wh[ks*32+koff(flag,h,j)][n]
// Wif: [dir][w][ks 0..3][tile 0..7][lane][16B], elem j -> Wi[ks*32+koff(flag,h,j)][n]
// n = G*256 + w*32 + nh*16 + (lane&15), tile = G*2+nh
__global__ __launch_bounds__(256) void prep_kernel(const float* Wh_f, const float* Wh_b,
    const float* Wi_f, const float* Wi_b, char* ws){
  const int flag = *(const int*)(ws + FLAG_OFF);
  int gid = blockIdx.x*256 + threadIdx.x;
  if (blockIdx.x < 256){
    int e = gid;
    int lane = e&63, tl = (e>>6)&7, ks = (e>>9)&7, w = (e>>12)&7, dir = (e>>15)&1;
    const float* Wh = dir ? Wh_b : Wh_f;
    int G = tl>>1, nh = tl&1;
    int nn = G*256 + w*32 + nh*16 + (lane&15);
    int h = lane>>4, kb = ks*32;
    int kj[8];
    #pragma unroll
    for (int j=0;j<8;j++) kj[j] = kb + koff(flag, h, j);
    int4 pv;
    pv.x = pack2(Wh[kj[0]*1024+nn], Wh[kj[1]*1024+nn]);
    pv.y = pack2(Wh[kj[2]*1024+nn], Wh[kj[3]*1024+nn]);
    pv.z = pack2(Wh[kj[4]*1024+nn], Wh[kj[5]*1024+nn]);
    pv.w = pack2(Wh[kj[6]*1024+nn], Wh[kj[7]*1024+nn]);
    ((int4*)(ws + WHF_OFF))[e] = pv;
  } else {
    int e = gid - 65536;
    int lane = e&63, tl = (e>>6)&7, ks = (e>>9)&3, w = (e>>11)&7, dir = (e>>14)&1;
    const float* Wi = dir ? Wi_b : Wi_f;
    int G = tl>>1, nh = tl&1;
    int nn = G*256 + w*32 + nh*16 + (lane&15);
    int h = lane>>4, kb = ks*32;
    int kj[8];
    #pragma unroll
    for (int j=0;j<8;j++) kj[j] = kb + koff(flag, h, j);
    int4 pv;
    pv.x = pack2(Wi[kj[0]*1024+nn], Wi[kj[1]*1024+nn]);
    pv.y = pack2(Wi[kj[2]*1024+nn], Wi[kj[3]*1024+nn]);
    pv.z = pack2(Wi[kj[4]*1024+nn], Wi[kj[5]*1024+nn]);
    pv.w = pack2(Wi[kj[6]*1024+nn], Wi[kj[7]*1024+nn]);
    ((int4*)(ws + WIF_OFF))[e] = pv;
  }
}

// ---------------- embed: x as A-fragments: XF[t][blk][ks][lane] 16B ---------
// elem j = bf16(emb[tok(b= blk*16+(lane&15), t)][ks*32 + koff(flag,h,j)])
__global__ __launch_bounds__(256) void embed_kernel(const int* tokens, const float* emb,
    char* ws){
  const int flag = *(const int*)(ws + FLAG_OFF);
  int e = blockIdx.x;               // 8192 = t*16 + blk
  int t = e >> 4, blk = e & 15;
  int tid = threadIdx.x;
  int ks = tid >> 6, lane = tid & 63;
  int h = lane >> 4, m = lane & 15;
  int b = blk*16 + m;
  int tok = tokens[b*S_LEN + t];
  const float* er = emb + (size_t)tok*128 + ks*32;
  float4 v0, v1;
  if (flag){
    v0 = *(const float4*)(er + 8*h);
    v1 = *(const float4*)(er + 8*h + 4);
  } else {
    v0 = *(const float4*)(er + 4*h);
    v1 = *(const float4*)(er + 16 + 4*h);
  }
  int4 pv;
  pv.x = pack2(v0.x,v0.y); pv.y = pack2(v0.z,v0.w);
  pv.z = pack2(v1.x,v1.y); pv.w = pack2(v1.z,v1.w);
  ((int4*)(ws + XF_OFF))[((size_t)e*4 + ks)*64 + lane] = pv;
}

// ---------------- rnn: 32 persistent blocks, 512 steps ----------------------
// Unified chunk index cs=0..11: cs<4 -> Wi ks=cs (A = x-frag), cs>=4 -> Wh ks=cs-4
// (A = h-frag from LDS). B-frags streamed from L2 via rotate-3 buffer; since
// weights are time-invariant the rotation wraps across steps.
__device__ __forceinline__ void lstm_step(
    int t, int dir, int blk, int w, int l, int flag,
    const int4* xf4, const int4* wif, const int4* whf,
    int4 (&xfUse)[4], int4 (&xfPre)[4],
    int4 (&bq)[3][8],
    const float (&bias)[8],
    const short* hRead, short* hWrite,
    float (&c)[8])
{
  // prefetch x-frags for t+1 (clamped; lands during this step's compute)
  int tn = (t+1 < S_LEN) ? t+1 : t;
  int tt = dir ? (S_LEN-1-tn) : tn;
  size_t xi = (((size_t)tt*16 + blk)*4)*64 + l;
  xfPre[0] = xf4[xi];     xfPre[1] = xf4[xi+64];
  xfPre[2] = xf4[xi+128]; xfPre[3] = xf4[xi+192];

  f32x4 acc[8];
  #pragma unroll
  for (int tl=0; tl<8; tl++){
    f32x4 v = {bias[tl],bias[tl],bias[tl],bias[tl]}; acc[tl] = v;
  }
  // h A-fragments from LDS (row m = l&15)
  bf16x8 a[8];
  #pragma unroll
  for (int ks=0; ks<8; ks++)
    a[ks] = loadA(hRead + (l&15)*264, ks*32, l>>4, flag);

  #pragma unroll
  for (int cs=0; cs<12; cs++){
    bf16x8 af = (cs < 4) ? __builtin_bit_cast(bf16x8, xfUse[cs]) : a[cs-4];
    #pragma unroll
    for (int tl=0; tl<8; tl++)
      acc[tl] = __builtin_amdgcn_mfma_f32_16x16x32_bf16(af,
                  __builtin_bit_cast(bf16x8, bq[cs%3][tl]), acc[tl], 0,0,0);
    const int nc = (cs+3) % 12;   // compile-time per unrolled iteration
    const int4* src = (nc < 4) ? (wif + (size_t)(nc*8)*64)
                               : (whf + (size_t)((nc-4)*8)*64);
    #pragma unroll
    for (int tl=0; tl<8; tl++)
      bq[cs%3][tl] = src[(size_t)tl*64 + l];
  }
  // gates: tiles tl = G*2+nh, G in {i,f,g,o}
  #pragma unroll
  for (int nh=0; nh<2; nh++){
    #pragma unroll
    for (int r=0; r<4; r++){
      const int ci = nh*4 + r;
      float iv = acc[0+nh][r];
      float fv = acc[2+nh][r];
      float gv = acc[4+nh][r];
      float ov = acc[6+nh][r];
      float cc = fsig(fv)*c[ci] + fsig(iv)*ftanh(gv);
      c[ci] = cc;
      float hh = fsig(ov)*ftanh(cc);
      hWrite[(4*(l>>4)+r)*264 + w*32 + nh*16 + (l&15)] = f2bf(hh);
    }
  }
  __syncthreads();
}

__global__ __launch_bounds__(512,2) void rnn_kernel(const float* b_f, const float* b_b,
    char* ws){
  const int flag = *(const int*)(ws + FLAG_OFF);
  int bid = blockIdx.x; int dir = bid>>4, blk = bid&15;
  int tid = threadIdx.x; int w = tid>>6, l = tid&63;
  __shared__ short hbuf[2][16*264];
  for (int i=tid; i<16*264; i+=512) hbuf[0][i] = 0;
  const int4* xf4 = (const int4*)(ws + XF_OFF);
  const int4* whf = (const int4*)(ws + WHF_OFF) + ((size_t)dir*8 + w)*8*8*64;
  const int4* wif = (const int4*)(ws + WIF_OFF) + ((size_t)dir*8 + w)*4*8*64;
  float bias[8];
  {
    const float* bh = dir ? b_b : b_f;
    #pragma unroll
    for (int tl=0;tl<8;tl++){
      int G = tl>>1, nh = tl&1;
      bias[tl] = bh[G*256 + w*32 + nh*16 + (l&15)];
    }
  }
  float c[8] = {0,0,0,0,0,0,0,0};
  int4 xqA[4], xqB[4], bq[3][8];
  {
    int tt0 = dir ? (S_LEN-1) : 0;
    size_t xi0 = (((size_t)tt0*16 + blk)*4)*64 + l;
    xqA[0]=xf4[xi0];     xqA[1]=xf4[xi0+64];
    xqA[2]=xf4[xi0+128]; xqA[3]=xf4[xi0+192];
  }
  #pragma unroll
  for (int kp=0;kp<3;kp++)
    #pragma unroll
    for (int tl=0;tl<8;tl++) bq[kp][tl] = wif[(size_t)(kp*8+tl)*64 + l];
  __syncthreads();
  #pragma unroll 1
  for (int t=0; t<S_LEN; t+=2){
    lstm_step(t,   dir, blk, w, l, flag, xf4, wif, whf, xqA, xqB, bq, bias, hbuf[0], hbuf[1], c);
    lstm_step(t+1, dir, blk, w, l, flag, xf4, wif, whf, xqB, xqA, bq, bias, hbuf[1], hbuf[0], c);
  }
  float* feat = (float*)(ws + FEAT_OFF);
  #pragma unroll
  for (int nh=0; nh<2; nh++)
    #pragma unroll
    for (int r=0; r<4; r++)
      feat[((size_t)blk*16 + 4*(l>>4)+r)*512 + dir*256 + w*32 + nh*16 + (l&15)] = c[nh*4+r];
}

// ---------------- head: feat@Wd+bd ------------------------------------------
__global__ __launch_bounds__(256) void head_kernel(const float* Wd, const float* bd,
    const char* ws, float* out){
  __shared__ float wds[4096];
  int tid = threadIdx.x;
  for (int i=tid; i<4096; i+=256) wds[i] = Wd[i];
  __syncthreads();
  if (tid < 128){
    int row = blockIdx.x*16 + (tid>>3), col = tid&7;
    const float* fr = (const float*)(ws + FEAT_OFF) + (size_t)row*512;
    float s = bd[col];
    #pragma unroll 8
    for (int k=0;k<512;k++) s += fr[k]*wds[k*8+col];
    out[row*8+col] = s;
  }
}

extern "C" void kernel_launch(void* const* d_in, const int* in_sizes, int n_in,
                              void* d_out, int out_size, void* d_ws, size_t ws_size,
                              hipStream_t stream) {
  const int*   tokens = (const int*)d_in[0];
  const float* emb    = (const float*)d_in[1];
  const float* Wi_f   = (const float*)d_in[2];
  const float* Wh_f   = (const float*)d_in[3];
  const float* b_f    = (const float*)d_in[4];
  const float* Wi_b   = (const float*)d_in[5];
  const float* Wh_b   = (const float*)d_in[6];
  const float* b_b    = (const float*)d_in[7];
  const float* Wd     = (const float*)d_in[8];
  const float* bd     = (const float*)d_in[9];
  char* ws = (char*)d_ws;
  float* out = (float*)d_out;

  if (ws_size < WS_NEED) return;   // avoid OOB fault; fails cleanly instead

  hipLaunchKernelGGL(probe_kernel, dim3(1),    dim3(64),  0, stream, ws);
  hipLaunchKernelGGL(prep_kernel,  dim3(384),  dim3(256), 0, stream, Wh_f, Wh_b, Wi_f, Wi_b, ws);
  hipLaunchKernelGGL(embed_kernel, dim3(8192), dim3(256), 0, stream, tokens, emb, ws);
  hipLaunchKernelGGL(rnn_kernel,   dim3(32),   dim3(512), 0, stream, b_f, b_b, ws);
  hipLaunchKernelGGL(head_kernel,  dim3(16),   dim3(256), 0, stream, Wd, bd, ws, out);
}